// Round 11
// baseline (18.196 us; speedup 1.0000x reference)
//
#include <hip/hip_runtime.h>
#include <math.h>

#define DIM 512
#define BATCH 1024
#define NPAIR (DIM * (DIM - 1) / 2)
#define TPB 512

typedef short bf16x8 __attribute__((ext_vector_type(8)));
typedef float f32x4  __attribute__((ext_vector_type(4)));

// ---- bf16 split helpers (RTN-even) ----
__device__ __forceinline__ unsigned short f2bf(float f) {
    unsigned int u = __float_as_uint(f);
    u += 0x7fff + ((u >> 16) & 1);
    return (unsigned short)(u >> 16);
}
__device__ __forceinline__ float bf2f(unsigned short h) {
    return __uint_as_float(((unsigned int)h) << 16);
}

// ws layout (ushort elems unless noted):
//   Uth @ 0        : ushort[512*512]   U^T hi  (Uth[n*512+k] = hi(U[k][n]))
//   Utl @ 262144   : ushort[512*512]   U^T lo
//   Xh  @ 524288   : ushort[1024*512]
//   Xl  @ 1048576  : ushort[1024*512]
//   partial @ byte 3145728 : float[20][1024]
//   cnt     @ byte 3227648 : int[8]    per-mg arrival tickets (zeroed by prep)
#define UTL_OFF 262144
#define XH_OFF  524288
#define XL_OFF  1048576
#define PART_BYTE 3145728u
#define CNT_BYTE  (3145728u + 81920u)

// U[k][n] = Wp[roff(k)+n] for n>k ; Wsq[k] for n==k ; 0 for n<k
// roff(k) = k*(DIM-2) - k(k-1)/2 - 1 ; roff(k+1) = roff(k) + (DIM-2-k)

// ---------------- kernel 1: prep — split U^T and X to bf16 hi/lo; zero tickets ----------
__global__ __launch_bounds__(256)
void prep(const float* __restrict__ x, const float* __restrict__ W,
          unsigned short* __restrict__ Uth, unsigned short* __restrict__ Utl,
          unsigned short* __restrict__ Xh, unsigned short* __restrict__ Xl,
          int* __restrict__ cnt) {
    const int bid = blockIdx.x, tid = threadIdx.x;
    if (bid == 0 && tid < 8) cnt[tid] = 0;
    if (bid < 256) {
        // X conversion: 65536 threads x 8 elements, fully coalesced
        const int gid = bid * 256 + tid;
        const float4 v0 = ((const float4*)x)[(size_t)gid * 2];
        const float4 v1 = ((const float4*)x)[(size_t)gid * 2 + 1];
        const float vs[8] = {v0.x, v0.y, v0.z, v0.w, v1.x, v1.y, v1.z, v1.w};
        bf16x8 hv, lv;
        #pragma unroll
        for (int e = 0; e < 8; ++e) {
            unsigned short h = f2bf(vs[e]);
            hv[e] = (short)h;
            lv[e] = (short)f2bf(vs[e] - bf2f(h));
        }
        ((bf16x8*)Xh)[gid] = hv;
        ((bf16x8*)Xl)[gid] = lv;
    } else {
        // U^T conversion: 32768 threads; thread = (n, k-chunk of 8).
        // Lanes carry contiguous n -> Wp reads coalesced; write is one b128 per thread.
        const int u  = (bid - 256) * 256 + tid;
        const int n  = u & 511;
        const int kc = u >> 9;               // 0..63
        const int k0 = kc * 8;
        const float* Wp  = W + DIM;
        const float* Wsq = W + DIM + NPAIR;
        float vs[8];
        int k  = k0;
        int ro = k0 * (DIM - 2) - (k0 * (k0 - 1)) / 2 - 1;   // roff(k0)
        #pragma unroll
        for (int e = 0; e < 8; ++e) {
            const float wv = Wp[ro + n];     // always in-bounds (see roff bounds)
            vs[e] = (n > k) ? wv : ((n == k) ? Wsq[k] : 0.f);
            ro += DIM - 2 - k;
            ++k;
        }
        bf16x8 hv, lv;
        #pragma unroll
        for (int e = 0; e < 8; ++e) {
            unsigned short h = f2bf(vs[e]);
            hv[e] = (short)h;
            lv[e] = (short)f2bf(vs[e] - bf2f(h));
        }
        *(bf16x8*)(Uth + (size_t)n * DIM + k0) = hv;
        *(bf16x8*)(Utl + (size_t)n * DIM + k0) = lv;
    }
}

// ---------------- kernel 2: lean MFMA GEMM + fused dot + fence-free fan-in ----------------
// grid 160 = 8 mg x 20 p ; block 512 thr = 8 waves (4 wm x 2 wn)
// block tile: 128 m x 128 n x 64 k ; wave 32m x 64n (2 sm x 4 sn of 16x16x32)
__global__ __launch_bounds__(TPB, 2)
void quad_gemm(const float* __restrict__ x, const float* __restrict__ W,
               const unsigned short* __restrict__ Uth, const unsigned short* __restrict__ Utl,
               const unsigned short* __restrict__ Xh, const unsigned short* __restrict__ Xl,
               const float* __restrict__ bias,
               float* __restrict__ partial, int* __restrict__ cnt,
               float* __restrict__ out) {
    const int bid = blockIdx.x;
    const int mg  = bid / 20;                  // row-group 0..7 (128 rows)
    const int p   = bid - mg * 20;
    const int n_blk = (p < 2) ? 0 : (p < 6) ? 1 : (p < 12) ? 2 : 3;
    const int kb    = (p < 2) ? 0 : (p < 6) ? 2 : (p < 12) ? 6 : 12;
    const int kspl  = p - kb;
    const int row0 = mg * 128, n0 = n_blk * 128, k0 = kspl * 64;

    const int tid = threadIdx.x;
    const int lane = tid & 63, w = tid >> 6;   // 8 waves
    const int wm = w >> 1, wn = w & 1;         // 4 x 2
    const int r15 = lane & 15, q = lane >> 4;

    __shared__ alignas(16) unsigned short sAh[128 * 64];
    __shared__ alignas(16) unsigned short sAl[128 * 64];
    __shared__ alignas(16) unsigned short sBh[128 * 64];
    __shared__ alignas(16) unsigned short sBl[128 * 64];
    __shared__ float ysum[2][128];             // [wn][m-in-block]
    __shared__ int lastFlag;

    // ---- A tile: pre-split Xh/Xl rows [row0,row0+128) x k-window; pure b128 copies ----
    #pragma unroll
    for (int s = 0; s < 2; ++s) {
        const int slot = tid + s * TPB;        // 0..1023
        const int row = slot >> 3, c = slot & 7;
        const int g    = (row0 + row) * DIM + k0 + c * 8;
        const int loff = row * 64 + ((c ^ (row & 7)) * 8);
        *(bf16x8*)(sAh + loff) = *(const bf16x8*)(Xh + g);
        *(bf16x8*)(sAl + loff) = *(const bf16x8*)(Xl + g);
    }
    // ---- B tile: pre-split U^T rows [n0,n0+128) x k-window; identical shape ----
    #pragma unroll
    for (int s = 0; s < 2; ++s) {
        const int slot = tid + s * TPB;
        const int row = slot >> 3, c = slot & 7;
        const int g    = (n0 + row) * DIM + k0 + c * 8;
        const int loff = row * 64 + ((c ^ (row & 7)) * 8);
        *(bf16x8*)(sBh + loff) = *(const bf16x8*)(Uth + g);
        *(bf16x8*)(sBl + loff) = *(const bf16x8*)(Utl + g);
    }

    // ---- prefetch epilogue operands (latency hides under barrier + MFMA) ----
    float xv[4][2][4];                          // [sn][sm][r]
    float wlv[4];
    #pragma unroll
    for (int sn = 0; sn < 4; ++sn) {
        const int n = n0 + wn * 64 + sn * 16 + r15;
        wlv[sn] = (kspl == 0) ? W[n] : 0.f;
        #pragma unroll
        for (int sm = 0; sm < 2; ++sm) {
            const int mbase = row0 + wm * 32 + sm * 16 + q * 4;
            #pragma unroll
            for (int r = 0; r < 4; ++r)
                xv[sn][sm][r] = x[(size_t)(mbase + r) * DIM + n];
        }
    }
    __syncthreads();

    // ---- 3-term bf16-split MFMA: T = Xh*Uh + Xl*Uh + Xh*Ul ----
    f32x4 acc[2][4];                            // [sm][sn]
    #pragma unroll
    for (int i = 0; i < 2; ++i)
        #pragma unroll
        for (int j = 0; j < 4; ++j) acc[i][j] = (f32x4){0.f, 0.f, 0.f, 0.f};

    #pragma unroll
    for (int ks = 0; ks < 2; ++ks) {
        const int c = ks * 4 + q;              // chunk-of-8 along k
        bf16x8 ah[2], al[2];
        #pragma unroll
        for (int sm = 0; sm < 2; ++sm) {
            const int row = wm * 32 + sm * 16 + r15;
            const int off = row * 64 + ((c ^ (row & 7)) * 8);
            ah[sm] = *(const bf16x8*)(sAh + off);
            al[sm] = *(const bf16x8*)(sAl + off);
        }
        #pragma unroll
        for (int sn = 0; sn < 4; ++sn) {
            const int row = wn * 64 + sn * 16 + r15;
            const int off = row * 64 + ((c ^ (row & 7)) * 8);
            const bf16x8 bh = *(const bf16x8*)(sBh + off);
            const bf16x8 bl = *(const bf16x8*)(sBl + off);
            acc[0][sn] = __builtin_amdgcn_mfma_f32_16x16x32_bf16(ah[0], bh, acc[0][sn], 0, 0, 0);
            acc[1][sn] = __builtin_amdgcn_mfma_f32_16x16x32_bf16(ah[1], bh, acc[1][sn], 0, 0, 0);
            acc[0][sn] = __builtin_amdgcn_mfma_f32_16x16x32_bf16(al[0], bh, acc[0][sn], 0, 0, 0);
            acc[1][sn] = __builtin_amdgcn_mfma_f32_16x16x32_bf16(al[1], bh, acc[1][sn], 0, 0, 0);
            acc[0][sn] = __builtin_amdgcn_mfma_f32_16x16x32_bf16(ah[0], bl, acc[0][sn], 0, 0, 0);
            acc[1][sn] = __builtin_amdgcn_mfma_f32_16x16x32_bf16(ah[1], bl, acc[1][sn], 0, 0, 0);
        }
    }

    // ---- fused epilogue: y_part[m] = sum_n (T + Wlin?) * x ----
    float yl[2][4];
    #pragma unroll
    for (int sm = 0; sm < 2; ++sm)
        #pragma unroll
        for (int r = 0; r < 4; ++r) yl[sm][r] = 0.f;

    #pragma unroll
    for (int sn = 0; sn < 4; ++sn)
        #pragma unroll
        for (int sm = 0; sm < 2; ++sm)
            #pragma unroll
            for (int r = 0; r < 4; ++r)
                yl[sm][r] += (acc[sm][sn][r] + wlv[sn]) * xv[sn][sm][r];

    #pragma unroll
    for (int off = 1; off < 16; off <<= 1) {
        #pragma unroll
        for (int sm = 0; sm < 2; ++sm)
            #pragma unroll
            for (int r = 0; r < 4; ++r)
                yl[sm][r] += __shfl_xor(yl[sm][r], off);
    }
    if (r15 == 0) {
        #pragma unroll
        for (int sm = 0; sm < 2; ++sm)
            #pragma unroll
            for (int r = 0; r < 4; ++r)
                ysum[wn][wm * 32 + sm * 16 + q * 4 + r] = yl[sm][r];
    }
    __syncthreads();

    // ---- partial write: agent-scope atomic stores (coherent, NO wbl2 fence) ----
    if (tid < 128) {
        const float z = ysum[0][tid] + ysum[1][tid];
        __hip_atomic_store(&partial[(size_t)p * BATCH + row0 + tid], z,
                           __ATOMIC_RELAXED, __HIP_MEMORY_SCOPE_AGENT);
    }
    asm volatile("s_waitcnt vmcnt(0)" ::: "memory");   // my stores are at coherence point
    __syncthreads();
    if (tid == 0) {
        const int old = __hip_atomic_fetch_add(&cnt[mg], 1,
                                               __ATOMIC_RELAXED, __HIP_MEMORY_SCOPE_AGENT);
        lastFlag = (old == 19);
    }
    __syncthreads();

    // ---- 20th arriver per mg: fixed-order sum via agent-scope atomic loads ----
    if (lastFlag && tid < 128) {
        float z = bias[0];
        #pragma unroll
        for (int s = 0; s < 20; ++s)
            z += __hip_atomic_load(&partial[(size_t)s * BATCH + row0 + tid],
                                   __ATOMIC_RELAXED, __HIP_MEMORY_SCOPE_AGENT);
        out[row0 + tid] = 1.0f / (1.0f + expf(-z));
    }
}

extern "C" void kernel_launch(void* const* d_in, const int* in_sizes, int n_in,
                              void* d_out, int out_size, void* d_ws, size_t ws_size,
                              hipStream_t stream) {
    const float* x = (const float*)d_in[0];   // [1024, 512]
    const float* W = (const float*)d_in[1];   // [1, 131840]
    const float* b = (const float*)d_in[2];   // [1]
    float* out = (float*)d_out;               // [1024]

    unsigned short* us = (unsigned short*)d_ws;
    unsigned short* Uth = us;
    unsigned short* Utl = us + UTL_OFF;
    unsigned short* Xh  = us + XH_OFF;
    unsigned short* Xl  = us + XL_OFF;
    float* partial = (float*)((char*)d_ws + PART_BYTE);
    int*   cnt     = (int*)((char*)d_ws + CNT_BYTE);

    hipLaunchKernelGGL(prep,      dim3(384), dim3(256), 0, stream, x, W, Uth, Utl, Xh, Xl, cnt);
    hipLaunchKernelGGL(quad_gemm, dim3(160), dim3(TPB), 0, stream, x, W, Uth, Utl, Xh, Xl,
                       b, partial, cnt, out);
}

// Round 12
// 12.502 us; speedup vs baseline: 1.4555x; 1.4555x over previous
//
#include <hip/hip_runtime.h>
#include <math.h>

#define DIM 512
#define BATCH 1024
#define NPAIR (DIM * (DIM - 1) / 2)
#define TPB 512

typedef short bf16x8 __attribute__((ext_vector_type(8)));
typedef float f32x4  __attribute__((ext_vector_type(4)));

// ---- bf16 split helpers (RTN-even) ----
__device__ __forceinline__ unsigned short f2bf(float f) {
    unsigned int u = __float_as_uint(f);
    u += 0x7fff + ((u >> 16) & 1);
    return (unsigned short)(u >> 16);
}
__device__ __forceinline__ float bf2f(unsigned short h) {
    return __uint_as_float(((unsigned int)h) << 16);
}

// ws: partial float[20][1024] (80 KB). slot = p.
// Upper-triangular U: U[k][n] = Wp[roff(k)+n] for n>k, Wsq[k] for n==k, 0 for n<k.
// roff(k) = k*(DIM-2) - k(k-1)/2 - 1 ; roff(k+1)-roff(k) = DIM-2-k.
// Tile list per 128-row group: n_blk {0,1,2,3} x kwin {2,4,6,8} -> 20 tiles.

// grid 160 = 8 mg x 20 p ; block 512 thr = 8 waves (4 wm x 2 wn) -> 1 block/CU, 1 round
// block tile: 128 m x 128 n x 64 k ; wave 32m x 64n (2 sm x 4 sn of 16x16x32)
__global__ __launch_bounds__(TPB, 2)
void quad_gemm(const float* __restrict__ x, const float* __restrict__ W,
               float* __restrict__ partial) {
    const int bid = blockIdx.x;
    const int mg  = bid / 20;                  // row-group 0..7 (128 rows)
    const int p   = bid - mg * 20;
    const int n_blk = (p < 2) ? 0 : (p < 6) ? 1 : (p < 12) ? 2 : 3;
    const int kb    = (p < 2) ? 0 : (p < 6) ? 2 : (p < 12) ? 6 : 12;
    const int kspl  = p - kb;
    const int row0 = mg * 128, n0 = n_blk * 128, k0 = kspl * 64;

    const int tid = threadIdx.x;
    const int lane = tid & 63, w = tid >> 6;   // 8 waves
    const int wm = w >> 1, wn = w & 1;         // 4 x 2
    const int r15 = lane & 15, q = lane >> 4;

    const float* Wp  = W + DIM;
    const float* Wsq = W + DIM + NPAIR;

    __shared__ alignas(16) unsigned short sAh[128 * 64];
    __shared__ alignas(16) unsigned short sAl[128 * 64];
    __shared__ alignas(16) unsigned short sBh[128 * 64];
    __shared__ alignas(16) unsigned short sBl[128 * 64];
    __shared__ float ysum[2][128];             // [wn][m-in-block]

    // ==== staging loads hoisted into registers first (max MLP at 1 block/CU) ====
    // A tile: x rows [row0,row0+128) x k-window; 16 el/thread
    float4 av[2][2];
    #pragma unroll
    for (int u = 0; u < 2; ++u) {
        const int row = (tid >> 3) + u * 64;   // 0..127
        const int c   = tid & 7;               // k-chunk 0..7
        const float* src = x + (size_t)(row0 + row) * DIM + k0 + c * 8;
        av[u][0] = *(const float4*)(src);
        av[u][1] = *(const float4*)(src + 4);
    }
    // B tile: U[k][n] gathered from packed triangle; 16 el/thread
    float bv[2][8];
    {
        const int nr = tid & 127;              // LDS row (n - n0)
        const int n  = n0 + nr;
        const int cb = (tid >> 7) * 2;         // chunk base {0,2,4,6}
        #pragma unroll
        for (int u = 0; u < 2; ++u) {
            const int c = cb + u;              // k-chunk 0..7
            int k  = k0 + c * 8;
            int ro = k * (DIM - 2) - (k * (k - 1)) / 2 - 1;   // roff(k)
            #pragma unroll
            for (int e = 0; e < 8; ++e) {
                const float wv = Wp[ro + n];   // coalesced across lanes (contig n)
                bv[u][e] = (n > k) ? wv : ((n == k) ? Wsq[k] : 0.f);
                ro += DIM - 2 - k;
                ++k;
            }
        }
    }

    // ==== convert + LDS write ====
    #pragma unroll
    for (int u = 0; u < 2; ++u) {
        const int row = (tid >> 3) + u * 64;
        const int c   = tid & 7;
        const float vs[8] = {av[u][0].x, av[u][0].y, av[u][0].z, av[u][0].w,
                             av[u][1].x, av[u][1].y, av[u][1].z, av[u][1].w};
        bf16x8 hv, lv;
        #pragma unroll
        for (int e = 0; e < 8; ++e) {
            unsigned short h = f2bf(vs[e]);
            hv[e] = (short)h;
            lv[e] = (short)f2bf(vs[e] - bf2f(h));
        }
        const int loff = row * 64 + ((c ^ (row & 7)) * 8);
        *(bf16x8*)(sAh + loff) = hv;
        *(bf16x8*)(sAl + loff) = lv;
    }
    {
        const int nr = tid & 127;
        const int cb = (tid >> 7) * 2;
        #pragma unroll
        for (int u = 0; u < 2; ++u) {
            const int c = cb + u;
            bf16x8 hv, lv;
            #pragma unroll
            for (int e = 0; e < 8; ++e) {
                unsigned short h = f2bf(bv[u][e]);
                hv[e] = (short)h;
                lv[e] = (short)f2bf(bv[u][e] - bf2f(h));
            }
            const int loff = nr * 64 + ((c ^ (nr & 7)) * 8);
            *(bf16x8*)(sBh + loff) = hv;
            *(bf16x8*)(sBl + loff) = lv;
        }
    }

    // ---- prefetch epilogue operands (latency hides under barrier + MFMA) ----
    float xv[4][2][4];                          // [sn][sm][r]
    float wlv[4];
    #pragma unroll
    for (int sn = 0; sn < 4; ++sn) {
        const int n = n0 + wn * 64 + sn * 16 + r15;
        wlv[sn] = (kspl == 0) ? W[n] : 0.f;
        #pragma unroll
        for (int sm = 0; sm < 2; ++sm) {
            const int mbase = row0 + wm * 32 + sm * 16 + q * 4;
            #pragma unroll
            for (int r = 0; r < 4; ++r)
                xv[sn][sm][r] = x[(size_t)(mbase + r) * DIM + n];
        }
    }
    __syncthreads();

    // ---- 3-term bf16-split MFMA: T = Xh*Uh + Xl*Uh + Xh*Ul ----
    f32x4 acc[2][4];                            // [sm][sn]
    #pragma unroll
    for (int i = 0; i < 2; ++i)
        #pragma unroll
        for (int j = 0; j < 4; ++j) acc[i][j] = (f32x4){0.f, 0.f, 0.f, 0.f};

    #pragma unroll
    for (int ks = 0; ks < 2; ++ks) {
        const int c = ks * 4 + q;              // chunk-of-8 along k
        bf16x8 ah[2], al[2];
        #pragma unroll
        for (int sm = 0; sm < 2; ++sm) {
            const int row = wm * 32 + sm * 16 + r15;
            const int off = row * 64 + ((c ^ (row & 7)) * 8);
            ah[sm] = *(const bf16x8*)(sAh + off);
            al[sm] = *(const bf16x8*)(sAl + off);
        }
        #pragma unroll
        for (int sn = 0; sn < 4; ++sn) {
            const int row = wn * 64 + sn * 16 + r15;
            const int off = row * 64 + ((c ^ (row & 7)) * 8);
            const bf16x8 bh = *(const bf16x8*)(sBh + off);
            const bf16x8 bl = *(const bf16x8*)(sBl + off);
            acc[0][sn] = __builtin_amdgcn_mfma_f32_16x16x32_bf16(ah[0], bh, acc[0][sn], 0, 0, 0);
            acc[1][sn] = __builtin_amdgcn_mfma_f32_16x16x32_bf16(ah[1], bh, acc[1][sn], 0, 0, 0);
            acc[0][sn] = __builtin_amdgcn_mfma_f32_16x16x32_bf16(al[0], bh, acc[0][sn], 0, 0, 0);
            acc[1][sn] = __builtin_amdgcn_mfma_f32_16x16x32_bf16(al[1], bh, acc[1][sn], 0, 0, 0);
            acc[0][sn] = __builtin_amdgcn_mfma_f32_16x16x32_bf16(ah[0], bl, acc[0][sn], 0, 0, 0);
            acc[1][sn] = __builtin_amdgcn_mfma_f32_16x16x32_bf16(ah[1], bl, acc[1][sn], 0, 0, 0);
        }
    }

    // ---- fused epilogue: y_part[m] = sum_n (T + Wlin?) * x ----
    float yl[2][4];
    #pragma unroll
    for (int sm = 0; sm < 2; ++sm)
        #pragma unroll
        for (int r = 0; r < 4; ++r) yl[sm][r] = 0.f;

    #pragma unroll
    for (int sn = 0; sn < 4; ++sn)
        #pragma unroll
        for (int sm = 0; sm < 2; ++sm)
            #pragma unroll
            for (int r = 0; r < 4; ++r)
                yl[sm][r] += (acc[sm][sn][r] + wlv[sn]) * xv[sn][sm][r];

    #pragma unroll
    for (int off = 1; off < 16; off <<= 1) {
        #pragma unroll
        for (int sm = 0; sm < 2; ++sm)
            #pragma unroll
            for (int r = 0; r < 4; ++r)
                yl[sm][r] += __shfl_xor(yl[sm][r], off);
    }
    if (r15 == 0) {
        #pragma unroll
        for (int sm = 0; sm < 2; ++sm)
            #pragma unroll
            for (int r = 0; r < 4; ++r)
                ysum[wn][wm * 32 + sm * 16 + q * 4 + r] = yl[sm][r];
    }
    __syncthreads();
    if (tid < 128) {
        const float z = ysum[0][tid] + ysum[1][tid];
        partial[(size_t)p * BATCH + row0 + tid] = z;
    }
}

// ---- finalize: fixed tree-sum of 20 slots + bias, sigmoid; 16 blocks for latency ----
__global__ __launch_bounds__(64)
void finalize(const float* __restrict__ partial, const float* __restrict__ bias,
              float* __restrict__ out) {
    const int t = blockIdx.x * 64 + threadIdx.x;
    float v[20];
    #pragma unroll
    for (int s = 0; s < 20; ++s) v[s] = partial[(size_t)s * BATCH + t];
    float z = (((v[0] + v[1]) + (v[2] + v[3])) + ((v[4] + v[5]) + (v[6] + v[7]))) +
              (((v[8] + v[9]) + (v[10] + v[11])) + ((v[12] + v[13]) + (v[14] + v[15]))) +
              ((v[16] + v[17]) + (v[18] + v[19])) + bias[0];
    out[t] = 1.0f / (1.0f + expf(-z));
}

extern "C" void kernel_launch(void* const* d_in, const int* in_sizes, int n_in,
                              void* d_out, int out_size, void* d_ws, size_t ws_size,
                              hipStream_t stream) {
    const float* x = (const float*)d_in[0];   // [1024, 512]
    const float* W = (const float*)d_in[1];   // [1, 131840]
    const float* b = (const float*)d_in[2];   // [1]
    float* out = (float*)d_out;               // [1024]

    float* partial = (float*)d_ws;            // 20*1024 floats, fully rewritten each call

    hipLaunchKernelGGL(quad_gemm, dim3(160), dim3(TPB), 0, stream, x, W, partial);
    hipLaunchKernelGGL(finalize,  dim3(BATCH / 64), dim3(64), 0, stream, partial, b, out);
}